// Round 12
// baseline (169.225 us; speedup 1.0000x reference)
//
#include <hip/hip_runtime.h>

// ---------------------------------------------------------------------------
// 2-layer GCN, CSR-gather, bf16 pre-scaled rows, MFMA GEMMs, atomic-free fill:
// out = log_softmax( Anorm @ relu(Anorm @ (x@W1) + b1) @ W2 + b2 )
// Anorm = D^-1/2 (A+I) D^-1/2.  Row r of each GEMM output is stored as
// bf16(dinv[r] * row); gather sums rows and multiplies by dinv[dst] once.
// CSR build: count pass (deg from 0 via memset; rank = atomic return value),
// scan, then atomic-free permutation fill csr[off[d]+rank[i]] = src[i],
// 4-way unrolled + XCD-partitioned, fused with the layer-1 MFMA GEMM.
// ---------------------------------------------------------------------------

constexpr int K1 = 128;
constexpr int SCAN_B = 256;

typedef short short8 __attribute__((ext_vector_type(8)));   // 8 bf16
typedef float f32x4 __attribute__((ext_vector_type(4)));

__device__ inline unsigned short f2b(float f) {  // f32 -> bf16 (round-nearest)
    unsigned u = __float_as_uint(f);
    u += 0x7fffu + ((u >> 16) & 1u);
    return (unsigned short)(u >> 16);
}

// count pass (deg = in-degree, rank = per-dst arrival order) fused with the
// W1/W2 transpose+bf16 convert (blocks >= ncount).
__global__ void k_count_rank(const int* __restrict__ dst, int e, int* __restrict__ deg,
                             unsigned short* __restrict__ rank,
                             const float* __restrict__ W1, const float* __restrict__ W2,
                             unsigned short* __restrict__ w1bt,
                             unsigned short* __restrict__ w2bt, int ncount) {
    int b = blockIdx.x;
    if (b < ncount) {
        int i = b * blockDim.x + threadIdx.x;
        if (i < e) {
            int p = atomicAdd(&deg[dst[i]], 1);
            rank[i] = (unsigned short)p;
        }
    } else {
        int i = (b - ncount) * blockDim.x + threadIdx.x;
        if (i < 128 * 128) {
            int c = i >> 7, k = i & 127;
            w1bt[i] = f2b(W1[k * 128 + c]);
        }
        if (i < 64 * 128) {
            int c = i >> 7, k = i & 127;
            w2bt[i] = f2b(W2[k * 64 + c]);
        }
    }
}

__global__ __launch_bounds__(SCAN_B) void k_scan_part(const int* __restrict__ deg,
                                                      int* __restrict__ blocksum, int n) {
    __shared__ int red[SCAN_B];
    int i = blockIdx.x * SCAN_B + threadIdx.x;
    int v = (i < n) ? deg[i] : 0;
    red[threadIdx.x] = v;
    __syncthreads();
    for (int o = SCAN_B / 2; o; o >>= 1) {
        if (threadIdx.x < o) red[threadIdx.x] += red[threadIdx.x + o];
        __syncthreads();
    }
    if (threadIdx.x == 0) blocksum[blockIdx.x] = red[0];
}

__global__ __launch_bounds__(1024) void k_scan_top(int* __restrict__ blocksum, int nb) {
    __shared__ int sh[1024];
    int t = threadIdx.x;
    int v = (t < nb) ? blocksum[t] : 0;
    sh[t] = v;
    __syncthreads();
    for (int o = 1; o < 1024; o <<= 1) {
        int u = (t >= o) ? sh[t - o] : 0;
        __syncthreads();
        sh[t] += u;
        __syncthreads();
    }
    if (t < nb) blocksum[t] = sh[t] - v;  // exclusive
}

__global__ __launch_bounds__(SCAN_B) void k_scan_final(const int* __restrict__ deg,
                                                       const int* __restrict__ blocksum,
                                                       int* __restrict__ off,
                                                       float* __restrict__ dinv, int n) {
    __shared__ int sh[SCAN_B];
    int t = threadIdx.x;
    int i = blockIdx.x * SCAN_B + t;
    int v = (i < n) ? deg[i] : 0;  // in-degree
    sh[t] = v;
    __syncthreads();
    for (int o = 1; o < SCAN_B; o <<= 1) {
        int u = (t >= o) ? sh[t - o] : 0;
        __syncthreads();
        sh[t] += u;
        __syncthreads();
    }
    if (i < n) {
        off[i] = blocksum[blockIdx.x] + sh[t] - v;
        dinv[i] = rsqrtf((float)(v + 1));  // +1 self loop
    }
}

// ---------------------------------------------------------------------------
// MFMA GEMM bodies.  C layout per 16x16x32 mfma: col = lane&15,
// row = (lane>>4)*4 + r.  A frag: row = lane&15, k = (lane>>4)*8 + i.
// ---------------------------------------------------------------------------
// f32 A input: Cb16[n,128] = bf16( dinv[r] * (A[n,128] @ W[128,128]) )
__device__ __forceinline__ void gemm128_body(int bid, const float* __restrict__ A,
                                             const unsigned short* __restrict__ Wbt,
                                             const float* __restrict__ dinv,
                                             unsigned short* __restrict__ Cb, int n) {
    constexpr int NT = 8;
    const int tid = threadIdx.x;
    const int wave = tid >> 6, lane = tid & 63;
    const int rowbase = bid * 128 + wave * 32;
    const int lrow = lane & 15;
    const int kgrp = lane >> 4;

    short8 a[2][4];
#pragma unroll
    for (int s = 0; s < 2; ++s)
#pragma unroll
        for (int kt = 0; kt < 4; ++kt) {
            int R = rowbase + 16 * s + lrow;
            int Rc = (R < n) ? R : (n - 1);
            const float* p = A + (size_t)Rc * 128 + kt * 32 + kgrp * 8;
            float4 u0 = *reinterpret_cast<const float4*>(p);
            float4 u1 = *reinterpret_cast<const float4*>(p + 4);
            short8 af;
            af[0] = (short)f2b(u0.x); af[1] = (short)f2b(u0.y);
            af[2] = (short)f2b(u0.z); af[3] = (short)f2b(u0.w);
            af[4] = (short)f2b(u1.x); af[5] = (short)f2b(u1.y);
            af[6] = (short)f2b(u1.z); af[7] = (short)f2b(u1.w);
            a[s][kt] = af;
        }

    f32x4 acc[2][NT];
#pragma unroll
    for (int s = 0; s < 2; ++s)
#pragma unroll
        for (int nt = 0; nt < NT; ++nt) acc[s][nt] = f32x4{0.f, 0.f, 0.f, 0.f};

#pragma unroll
    for (int nt = 0; nt < NT; ++nt) {
        short8 b[4];
#pragma unroll
        for (int kt = 0; kt < 4; ++kt)
            b[kt] = *reinterpret_cast<const short8*>(
                Wbt + (size_t)(nt * 16 + lrow) * 128 + kt * 32 + kgrp * 8);
#pragma unroll
        for (int s = 0; s < 2; ++s)
#pragma unroll
            for (int kt = 0; kt < 4; ++kt)
                acc[s][nt] = __builtin_amdgcn_mfma_f32_16x16x32_bf16(a[s][kt], b[kt],
                                                                     acc[s][nt], 0, 0, 0);
    }

#pragma unroll
    for (int s = 0; s < 2; ++s)
#pragma unroll
        for (int r = 0; r < 4; ++r) {
            int R = rowbase + 16 * s + kgrp * 4 + r;
            if (R < n) {
                float sc = dinv[R];
#pragma unroll
                for (int nt = 0; nt < NT; ++nt)
                    Cb[(size_t)R * 128 + nt * 16 + lrow] = f2b(sc * acc[s][nt][r]);
            }
        }
}

// bf16 A input (agg1): Cb16[n,64] = bf16( dinv[r] * (Ab[n,128] @ W[128,64]) )
__global__ __launch_bounds__(256) void k_gemm64(
    const unsigned short* __restrict__ Ab, const unsigned short* __restrict__ Wbt,
    const float* __restrict__ dinv, unsigned short* __restrict__ Cb, int n) {
    constexpr int NT = 4;
    const int tid = threadIdx.x;
    const int wave = tid >> 6, lane = tid & 63;
    const int rowbase = blockIdx.x * 128 + wave * 32;
    const int lrow = lane & 15;
    const int kgrp = lane >> 4;

    short8 a[2][4];
#pragma unroll
    for (int s = 0; s < 2; ++s)
#pragma unroll
        for (int kt = 0; kt < 4; ++kt) {
            int R = rowbase + 16 * s + lrow;
            int Rc = (R < n) ? R : (n - 1);
            a[s][kt] = *reinterpret_cast<const short8*>(
                Ab + (size_t)Rc * 128 + kt * 32 + kgrp * 8);
        }

    f32x4 acc[2][NT];
#pragma unroll
    for (int s = 0; s < 2; ++s)
#pragma unroll
        for (int nt = 0; nt < NT; ++nt) acc[s][nt] = f32x4{0.f, 0.f, 0.f, 0.f};

#pragma unroll
    for (int nt = 0; nt < NT; ++nt) {
        short8 b[4];
#pragma unroll
        for (int kt = 0; kt < 4; ++kt)
            b[kt] = *reinterpret_cast<const short8*>(
                Wbt + (size_t)(nt * 16 + lrow) * 128 + kt * 32 + kgrp * 8);
#pragma unroll
        for (int s = 0; s < 2; ++s)
#pragma unroll
            for (int kt = 0; kt < 4; ++kt)
                acc[s][nt] = __builtin_amdgcn_mfma_f32_16x16x32_bf16(a[s][kt], b[kt],
                                                                     acc[s][nt], 0, 0, 0);
    }

#pragma unroll
    for (int s = 0; s < 2; ++s)
#pragma unroll
        for (int r = 0; r < 4; ++r) {
            int R = rowbase + 16 * s + kgrp * 4 + r;
            if (R < n) {
                float sc = dinv[R];
#pragma unroll
                for (int nt = 0; nt < NT; ++nt)
                    Cb[(size_t)R * 64 + nt * 16 + lrow] = f2b(sc * acc[s][nt][r]);
            }
        }
}

// atomic-free, XCD-partitioned permutation fill; 4-way unrolled for MLP.
// nfill MUST be a multiple of 8; mapping uses b2&7 == blockIdx%8 -> one XCD
// per dst-partition (fill blocks come FIRST in the fused grid).
__device__ __forceinline__ void fill_body(int b2, int nfill, const int* __restrict__ src,
                                          const int* __restrict__ dst,
                                          const unsigned short* __restrict__ rank,
                                          const int* __restrict__ off,
                                          unsigned short* __restrict__ csr, int e, int n8) {
    const int part = b2 & 7;
    const int j = b2 >> 3;
    const int nsl = nfill >> 3;
    const int per = (e + nsl - 1) / nsl;
    const int lo = j * per;
    const int hi = (lo + per < e) ? lo + per : e;
    const int dlo = part * n8;
    const int dhi = dlo + n8;

    int i = lo + threadIdx.x;
    for (; i + 768 < hi; i += 1024) {
        int d0 = dst[i], d1 = dst[i + 256], d2 = dst[i + 512], d3 = dst[i + 768];
        int s0 = src[i], s1 = src[i + 256], s2 = src[i + 512], s3 = src[i + 768];
        unsigned short r0 = rank[i], r1 = rank[i + 256];
        unsigned short r2 = rank[i + 512], r3 = rank[i + 768];
        int o0 = off[d0], o1 = off[d1], o2 = off[d2], o3 = off[d3];
        if (d0 >= dlo && d0 < dhi) csr[o0 + r0] = (unsigned short)s0;
        if (d1 >= dlo && d1 < dhi) csr[o1 + r1] = (unsigned short)s1;
        if (d2 >= dlo && d2 < dhi) csr[o2 + r2] = (unsigned short)s2;
        if (d3 >= dlo && d3 < dhi) csr[o3 + r3] = (unsigned short)s3;
    }
    for (; i < hi; i += 256) {
        int d = dst[i];
        if (d >= dlo && d < dhi) csr[off[d] + rank[i]] = (unsigned short)src[i];
    }
}

// fused: blocks [0,nfill) do the CSR fill; [nfill, nfill+ngemm) do the
// layer-1 MFMA GEMM (independent work, overlapped).
__global__ __launch_bounds__(256) void k_gemm_fill(
    const float* __restrict__ A, const unsigned short* __restrict__ Wbt,
    const float* __restrict__ dinv, unsigned short* __restrict__ Cb, int n,
    const int* __restrict__ src, const int* __restrict__ dst,
    const unsigned short* __restrict__ rank, const int* __restrict__ off,
    unsigned short* __restrict__ csr, int e, int n8, int nfill) {
    if ((int)blockIdx.x < nfill)
        fill_body(blockIdx.x, nfill, src, dst, rank, off, csr, e, n8);
    else
        gemm128_body(blockIdx.x - nfill, A, Wbt, dinv, Cb, n);
}

// one wave per dst node. bf16 rows: quarter-wave (16 lanes x 8 bf16) covers a
// 128-col row -> 4 edges per VMEM, 2-deep unroll -> 8 rows in flight.
// agg[d] = bf16( relu( b + dinv[d] * (xb[d] + sum_e xb[src_e]) ) )
__global__ __launch_bounds__(256) void k_gather128(
    const int* __restrict__ off, const int* __restrict__ deg,
    const unsigned short* __restrict__ csr, const unsigned short* __restrict__ xb,
    const float* __restrict__ dinv, const float* __restrict__ b,
    unsigned short* __restrict__ agg, int n) {
    int wid = (blockIdx.x * blockDim.x + threadIdx.x) >> 6;
    int lane = threadIdx.x & 63;
    if (wid >= n) return;
    const int q = lane >> 4;
    const int c0 = (lane & 15) * 8;

    float a[8];
#pragma unroll
    for (int k = 0; k < 8; ++k) a[k] = 0.f;

    const int s0 = off[wid];
    const int cnt = deg[wid];  // in-degree

    int t = q;
    for (; t + 4 < cnt; t += 8) {
        int e0 = csr[s0 + t];
        int e1 = csr[s0 + t + 4];
        uint4 v0 = *reinterpret_cast<const uint4*>(xb + (size_t)e0 * 128 + c0);
        uint4 v1 = *reinterpret_cast<const uint4*>(xb + (size_t)e1 * 128 + c0);
#pragma unroll
        for (int j = 0; j < 4; ++j) {
            unsigned w0 = (&v0.x)[j];
            unsigned w1 = (&v1.x)[j];
            a[2 * j]     += __uint_as_float(w0 << 16);
            a[2 * j + 1] += __uint_as_float(w0 & 0xffff0000u);
            a[2 * j]     += __uint_as_float(w1 << 16);
            a[2 * j + 1] += __uint_as_float(w1 & 0xffff0000u);
        }
    }
    for (; t < cnt; t += 4) {
        int e0 = csr[s0 + t];
        uint4 v0 = *reinterpret_cast<const uint4*>(xb + (size_t)e0 * 128 + c0);
#pragma unroll
        for (int j = 0; j < 4; ++j) {
            unsigned w0 = (&v0.x)[j];
            a[2 * j]     += __uint_as_float(w0 << 16);
            a[2 * j + 1] += __uint_as_float(w0 & 0xffff0000u);
        }
    }

#pragma unroll
    for (int k = 0; k < 8; ++k) {
        a[k] += __shfl_xor(a[k], 16);
        a[k] += __shfl_xor(a[k], 32);
    }

    if (q == 0) {
        float di = dinv[wid];
        uint4 sv = *reinterpret_cast<const uint4*>(xb + (size_t)wid * 128 + c0);
        float4 bv0 = *reinterpret_cast<const float4*>(b + c0);
        float4 bv1 = *reinterpret_cast<const float4*>(b + c0 + 4);
        float o[8];
#pragma unroll
        for (int j = 0; j < 4; ++j) {
            unsigned w = (&sv.x)[j];
            o[2 * j]     = a[2 * j]     + __uint_as_float(w << 16);
            o[2 * j + 1] = a[2 * j + 1] + __uint_as_float(w & 0xffff0000u);
        }
        const float* bb = (const float*)&bv0;
        short8 st;
#pragma unroll
        for (int k = 0; k < 8; ++k) {
            float bk = (k < 4) ? bb[k] : ((const float*)&bv1)[k - 4];
            st[k] = (short)f2b(fmaxf(fmaf(di, o[k], bk), 0.f));
        }
        *reinterpret_cast<short8*>(agg + (size_t)wid * 128 + c0) = st;
    }
}

// one wave per dst node. bf16 rows of 64 cols: eighth-wave (8 lanes x 8 bf16)
// covers a row -> 8 edges per VMEM; log_softmax fused.
__global__ __launch_bounds__(256) void k_gather64_lsm(
    const int* __restrict__ off, const int* __restrict__ deg,
    const unsigned short* __restrict__ csr, const unsigned short* __restrict__ hb,
    const float* __restrict__ dinv, const float* __restrict__ b,
    float* __restrict__ out, int n) {
    int wid = (blockIdx.x * blockDim.x + threadIdx.x) >> 6;
    int lane = threadIdx.x & 63;
    if (wid >= n) return;
    const int oct = lane >> 3;
    const int c0 = (lane & 7) * 8;

    float a[8];
#pragma unroll
    for (int k = 0; k < 8; ++k) a[k] = 0.f;

    const int s0 = off[wid];
    const int cnt = deg[wid];  // in-degree

    int t = oct;
    for (; t + 8 < cnt; t += 16) {
        int e0 = csr[s0 + t];
        int e1 = csr[s0 + t + 8];
        uint4 v0 = *reinterpret_cast<const uint4*>(hb + (size_t)e0 * 64 + c0);
        uint4 v1 = *reinterpret_cast<const uint4*>(hb + (size_t)e1 * 64 + c0);
#pragma unroll
        for (int j = 0; j < 4; ++j) {
            unsigned w0 = (&v0.x)[j];
            unsigned w1 = (&v1.x)[j];
            a[2 * j]     += __uint_as_float(w0 << 16);
            a[2 * j + 1] += __uint_as_float(w0 & 0xffff0000u);
            a[2 * j]     += __uint_as_float(w1 << 16);
            a[2 * j + 1] += __uint_as_float(w1 & 0xffff0000u);
        }
    }
    for (; t < cnt; t += 8) {
        int e0 = csr[s0 + t];
        uint4 v0 = *reinterpret_cast<const uint4*>(hb + (size_t)e0 * 64 + c0);
#pragma unroll
        for (int j = 0; j < 4; ++j) {
            unsigned w0 = (&v0.x)[j];
            a[2 * j]     += __uint_as_float(w0 << 16);
            a[2 * j + 1] += __uint_as_float(w0 & 0xffff0000u);
        }
    }

#pragma unroll
    for (int k = 0; k < 8; ++k) {
        a[k] += __shfl_xor(a[k], 8);
        a[k] += __shfl_xor(a[k], 16);
        a[k] += __shfl_xor(a[k], 32);
    }

    float di = dinv[wid];
    uint4 sv = *reinterpret_cast<const uint4*>(hb + (size_t)wid * 64 + c0);
    float4 bv0 = *reinterpret_cast<const float4*>(b + c0);
    float4 bv1 = *reinterpret_cast<const float4*>(b + c0 + 4);
    float v[8];
#pragma unroll
    for (int j = 0; j < 4; ++j) {
        unsigned w = (&sv.x)[j];
        v[2 * j]     = a[2 * j]     + __uint_as_float(w << 16);
        v[2 * j + 1] = a[2 * j + 1] + __uint_as_float(w & 0xffff0000u);
    }
    v[0] = fmaf(di, v[0], bv0.x);
    v[1] = fmaf(di, v[1], bv0.y);
    v[2] = fmaf(di, v[2], bv0.z);
    v[3] = fmaf(di, v[3], bv0.w);
    v[4] = fmaf(di, v[4], bv1.x);
    v[5] = fmaf(di, v[5], bv1.y);
    v[6] = fmaf(di, v[6], bv1.z);
    v[7] = fmaf(di, v[7], bv1.w);

    float m = v[0];
#pragma unroll
    for (int k = 1; k < 8; ++k) m = fmaxf(m, v[k]);
    m = fmaxf(m, __shfl_xor(m, 1));
    m = fmaxf(m, __shfl_xor(m, 2));
    m = fmaxf(m, __shfl_xor(m, 4));

    float s = 0.f;
#pragma unroll
    for (int k = 0; k < 8; ++k) s += expf(v[k] - m);
    s += __shfl_xor(s, 1);
    s += __shfl_xor(s, 2);
    s += __shfl_xor(s, 4);
    float ls = m + logf(s);

    if (oct == 0) {
        float4 r0, r1;
        r0.x = v[0] - ls; r0.y = v[1] - ls; r0.z = v[2] - ls; r0.w = v[3] - ls;
        r1.x = v[4] - ls; r1.y = v[5] - ls; r1.z = v[6] - ls; r1.w = v[7] - ls;
        *reinterpret_cast<float4*>(out + (size_t)wid * 64 + c0) = r0;
        *reinterpret_cast<float4*>(out + (size_t)wid * 64 + c0 + 4) = r1;
    }
}

extern "C" void kernel_launch(void* const* d_in, const int* in_sizes, int n_in,
                              void* d_out, int out_size, void* d_ws, size_t ws_size,
                              hipStream_t stream) {
    const float* x  = (const float*)d_in[0];
    const int*   ei = (const int*)d_in[1];
    const float* W1 = (const float*)d_in[2];
    const float* b1 = (const float*)d_in[3];
    const float* W2 = (const float*)d_in[4];
    const float* b2 = (const float*)d_in[5];

    const int n = in_sizes[0] / K1;   // 50000
    const int e = in_sizes[1] / 2;    // 800000
    const int* src = ei;
    const int* dst = ei + e;
    float* out = (float*)d_out;

    const int nb_scan = (n + SCAN_B - 1) / SCAN_B;  // 196 (<=1024)
    const int n8 = (n + 7) / 8;
    const int ngemm = (n + 127) / 128;              // 391 gemm blocks
    const int nfill = 2048;                         // multiple of 8
    const int ncount = (e + 255) / 256;
    const int nwcvt = (128 * 128 + 255) / 256;      // 64 blocks cover both W

    // ws layout (u16 unless noted):
    // agg1[n*128] | xb16[n*128] | hb16[n*64] | deg[n] int | dinv[n] f32 |
    // off[n] int | blocksum int | w1bt[16384] | w2bt[8192] | rank[e] | csr[e]
    unsigned short* agg1     = (unsigned short*)d_ws;
    unsigned short* xb16     = agg1 + (size_t)n * 128;
    unsigned short* hb16     = xb16 + (size_t)n * 128;
    int*            deg      = (int*)(hb16 + (size_t)n * 64);
    float*          dinv     = (float*)(deg + n);
    int*            off      = (int*)(dinv + n);
    int*            blocksum = off + n;
    unsigned short* w1bt     = (unsigned short*)(((uintptr_t)(blocksum + nb_scan) + 15) &
                                                 ~(uintptr_t)15);
    unsigned short* w2bt     = w1bt + 128 * 128;
    unsigned short* rank     = w2bt + 64 * 128;
    unsigned short* csr      = rank + e;

    const int B = 256;

    hipMemsetAsync(deg, 0, (size_t)n * sizeof(int), stream);
    k_count_rank<<<ncount + nwcvt, B, 0, stream>>>(dst, e, deg, rank, W1, W2,
                                                   w1bt, w2bt, ncount);
    k_scan_part<<<nb_scan, SCAN_B, 0, stream>>>(deg, blocksum, n);
    k_scan_top<<<1, 1024, 0, stream>>>(blocksum, nb_scan);
    k_scan_final<<<nb_scan, SCAN_B, 0, stream>>>(deg, blocksum, off, dinv, n);

    // CSR fill (atomic-free) fused with layer-1 MFMA GEMM; fill blocks first.
    k_gemm_fill<<<nfill + ngemm, B, 0, stream>>>(x, w1bt, dinv, xb16, n,
                                                 src, dst, rank, off, csr, e, n8, nfill);

    k_gather128<<<(n + 3) / 4, B, 0, stream>>>(off, deg, csr, xb16, dinv, b1, agg1, n);

    k_gemm64<<<ngemm, B, 0, stream>>>(agg1, w2bt, dinv, hb16, n);
    k_gather64_lsm<<<(n + 3) / 4, B, 0, stream>>>(off, deg, csr, hb16, dinv, b2, out, n);
}

// Round 13
// 145.935 us; speedup vs baseline: 1.1596x; 1.1596x over previous
//
#include <hip/hip_runtime.h>

// ---------------------------------------------------------------------------
// 2-layer GCN, CSR-gather, bf16 pre-scaled rows, MFMA GEMMs, atomic-free fill:
// out = log_softmax( Anorm @ relu(Anorm @ (x@W1) + b1) @ W2 + b2 )
// Anorm = D^-1/2 (A+I) D^-1/2.  Row r of each GEMM output is stored as
// bf16(dinv[r] * row); gather sums rows and multiplies by dinv[dst] once.
// CSR build: count pass (rank = atomic return value), scan, then atomic-free
// one-edge-per-thread permutation fill csr[off[dst]]+rank] = src (no loops,
// max TLP). Layer-1 MFMA GEMM rides in the fill dispatch, gemm blocks first.
// ---------------------------------------------------------------------------

constexpr int K1 = 128;
constexpr int SCAN_B = 256;

typedef short short8 __attribute__((ext_vector_type(8)));   // 8 bf16
typedef float f32x4 __attribute__((ext_vector_type(4)));

__device__ inline unsigned short f2b(float f) {  // f32 -> bf16 (round-nearest)
    unsigned u = __float_as_uint(f);
    u += 0x7fffu + ((u >> 16) & 1u);
    return (unsigned short)(u >> 16);
}

// W1/W2 transpose+bf16 convert (blocks [0,nwcvt)) fused with the count pass
// (deg = in-degree histogram, rank = per-dst arrival order).
__global__ void k_count_w(const int* __restrict__ dst, int e, int* __restrict__ deg,
                          unsigned short* __restrict__ rank,
                          const float* __restrict__ W1, const float* __restrict__ W2,
                          unsigned short* __restrict__ w1bt,
                          unsigned short* __restrict__ w2bt, int nwcvt) {
    int b = blockIdx.x;
    if (b < nwcvt) {
        int i = b * blockDim.x + threadIdx.x;
        if (i < 128 * 128) {
            int c = i >> 7, k = i & 127;
            w1bt[i] = f2b(W1[k * 128 + c]);
        }
        if (i < 64 * 128) {
            int c = i >> 7, k = i & 127;
            w2bt[i] = f2b(W2[k * 64 + c]);
        }
    } else {
        int i = (b - nwcvt) * blockDim.x + threadIdx.x;
        if (i < e) {
            int p = atomicAdd(&deg[dst[i]], 1);
            rank[i] = (unsigned short)p;
        }
    }
}

__global__ __launch_bounds__(SCAN_B) void k_scan_part(const int* __restrict__ deg,
                                                      int* __restrict__ blocksum, int n) {
    __shared__ int red[SCAN_B];
    int i = blockIdx.x * SCAN_B + threadIdx.x;
    int v = (i < n) ? deg[i] : 0;
    red[threadIdx.x] = v;
    __syncthreads();
    for (int o = SCAN_B / 2; o; o >>= 1) {
        if (threadIdx.x < o) red[threadIdx.x] += red[threadIdx.x + o];
        __syncthreads();
    }
    if (threadIdx.x == 0) blocksum[blockIdx.x] = red[0];
}

__global__ __launch_bounds__(1024) void k_scan_top(int* __restrict__ blocksum, int nb) {
    __shared__ int sh[1024];
    int t = threadIdx.x;
    int v = (t < nb) ? blocksum[t] : 0;
    sh[t] = v;
    __syncthreads();
    for (int o = 1; o < 1024; o <<= 1) {
        int u = (t >= o) ? sh[t - o] : 0;
        __syncthreads();
        sh[t] += u;
        __syncthreads();
    }
    if (t < nb) blocksum[t] = sh[t] - v;  // exclusive
}

__global__ __launch_bounds__(SCAN_B) void k_scan_final(const int* __restrict__ deg,
                                                       const int* __restrict__ blocksum,
                                                       int* __restrict__ off,
                                                       float* __restrict__ dinv, int n) {
    __shared__ int sh[SCAN_B];
    int t = threadIdx.x;
    int i = blockIdx.x * SCAN_B + t;
    int v = (i < n) ? deg[i] : 0;  // in-degree
    sh[t] = v;
    __syncthreads();
    for (int o = 1; o < SCAN_B; o <<= 1) {
        int u = (t >= o) ? sh[t - o] : 0;
        __syncthreads();
        sh[t] += u;
        __syncthreads();
    }
    if (i < n) {
        off[i] = blocksum[blockIdx.x] + sh[t] - v;
        dinv[i] = rsqrtf((float)(v + 1));  // +1 self loop
    }
}

// ---------------------------------------------------------------------------
// MFMA GEMM bodies.  C layout per 16x16x32 mfma: col = lane&15,
// row = (lane>>4)*4 + r.  A frag: row = lane&15, k = (lane>>4)*8 + i.
// ---------------------------------------------------------------------------
// f32 A input: Cb16[n,128] = bf16( dinv[r] * (A[n,128] @ W[128,128]) )
__device__ __forceinline__ void gemm128_body(int bid, const float* __restrict__ A,
                                             const unsigned short* __restrict__ Wbt,
                                             const float* __restrict__ dinv,
                                             unsigned short* __restrict__ Cb, int n) {
    constexpr int NT = 8;
    const int tid = threadIdx.x;
    const int wave = tid >> 6, lane = tid & 63;
    const int rowbase = bid * 128 + wave * 32;
    const int lrow = lane & 15;
    const int kgrp = lane >> 4;

    short8 a[2][4];
#pragma unroll
    for (int s = 0; s < 2; ++s)
#pragma unroll
        for (int kt = 0; kt < 4; ++kt) {
            int R = rowbase + 16 * s + lrow;
            int Rc = (R < n) ? R : (n - 1);
            const float* p = A + (size_t)Rc * 128 + kt * 32 + kgrp * 8;
            float4 u0 = *reinterpret_cast<const float4*>(p);
            float4 u1 = *reinterpret_cast<const float4*>(p + 4);
            short8 af;
            af[0] = (short)f2b(u0.x); af[1] = (short)f2b(u0.y);
            af[2] = (short)f2b(u0.z); af[3] = (short)f2b(u0.w);
            af[4] = (short)f2b(u1.x); af[5] = (short)f2b(u1.y);
            af[6] = (short)f2b(u1.z); af[7] = (short)f2b(u1.w);
            a[s][kt] = af;
        }

    f32x4 acc[2][NT];
#pragma unroll
    for (int s = 0; s < 2; ++s)
#pragma unroll
        for (int nt = 0; nt < NT; ++nt) acc[s][nt] = f32x4{0.f, 0.f, 0.f, 0.f};

#pragma unroll
    for (int nt = 0; nt < NT; ++nt) {
        short8 b[4];
#pragma unroll
        for (int kt = 0; kt < 4; ++kt)
            b[kt] = *reinterpret_cast<const short8*>(
                Wbt + (size_t)(nt * 16 + lrow) * 128 + kt * 32 + kgrp * 8);
#pragma unroll
        for (int s = 0; s < 2; ++s)
#pragma unroll
            for (int kt = 0; kt < 4; ++kt)
                acc[s][nt] = __builtin_amdgcn_mfma_f32_16x16x32_bf16(a[s][kt], b[kt],
                                                                     acc[s][nt], 0, 0, 0);
    }

#pragma unroll
    for (int s = 0; s < 2; ++s)
#pragma unroll
        for (int r = 0; r < 4; ++r) {
            int R = rowbase + 16 * s + kgrp * 4 + r;
            if (R < n) {
                float sc = dinv[R];
#pragma unroll
                for (int nt = 0; nt < NT; ++nt)
                    Cb[(size_t)R * 128 + nt * 16 + lrow] = f2b(sc * acc[s][nt][r]);
            }
        }
}

// bf16 A input (agg1): Cb16[n,64] = bf16( dinv[r] * (Ab[n,128] @ W[128,64]) )
__global__ __launch_bounds__(256) void k_gemm64(
    const unsigned short* __restrict__ Ab, const unsigned short* __restrict__ Wbt,
    const float* __restrict__ dinv, unsigned short* __restrict__ Cb, int n) {
    constexpr int NT = 4;
    const int tid = threadIdx.x;
    const int wave = tid >> 6, lane = tid & 63;
    const int rowbase = blockIdx.x * 128 + wave * 32;
    const int lrow = lane & 15;
    const int kgrp = lane >> 4;

    short8 a[2][4];
#pragma unroll
    for (int s = 0; s < 2; ++s)
#pragma unroll
        for (int kt = 0; kt < 4; ++kt) {
            int R = rowbase + 16 * s + lrow;
            int Rc = (R < n) ? R : (n - 1);
            a[s][kt] = *reinterpret_cast<const short8*>(
                Ab + (size_t)Rc * 128 + kt * 32 + kgrp * 8);
        }

    f32x4 acc[2][NT];
#pragma unroll
    for (int s = 0; s < 2; ++s)
#pragma unroll
        for (int nt = 0; nt < NT; ++nt) acc[s][nt] = f32x4{0.f, 0.f, 0.f, 0.f};

#pragma unroll
    for (int nt = 0; nt < NT; ++nt) {
        short8 b[4];
#pragma unroll
        for (int kt = 0; kt < 4; ++kt)
            b[kt] = *reinterpret_cast<const short8*>(
                Wbt + (size_t)(nt * 16 + lrow) * 128 + kt * 32 + kgrp * 8);
#pragma unroll
        for (int s = 0; s < 2; ++s)
#pragma unroll
            for (int kt = 0; kt < 4; ++kt)
                acc[s][nt] = __builtin_amdgcn_mfma_f32_16x16x32_bf16(a[s][kt], b[kt],
                                                                     acc[s][nt], 0, 0, 0);
    }

#pragma unroll
    for (int s = 0; s < 2; ++s)
#pragma unroll
        for (int r = 0; r < 4; ++r) {
            int R = rowbase + 16 * s + kgrp * 4 + r;
            if (R < n) {
                float sc = dinv[R];
#pragma unroll
                for (int nt = 0; nt < NT; ++nt)
                    Cb[(size_t)R * 64 + nt * 16 + lrow] = f2b(sc * acc[s][nt][r]);
            }
        }
}

// fused: blocks [0,ngemm) do the layer-1 MFMA GEMM (co-resident with fill
// from dispatch 0 -> true overlap); blocks [ngemm,..) do the atomic-free
// one-edge-per-thread permutation fill (no loops, max TLP).
__global__ __launch_bounds__(256) void k_gemm_fill(
    const float* __restrict__ A, const unsigned short* __restrict__ Wbt,
    const float* __restrict__ dinv, unsigned short* __restrict__ Cb, int n,
    const int* __restrict__ src, const int* __restrict__ dst,
    const unsigned short* __restrict__ rank, const int* __restrict__ off,
    unsigned short* __restrict__ csr, int e, int ngemm) {
    int b = blockIdx.x;
    if (b < ngemm) {
        gemm128_body(b, A, Wbt, dinv, Cb, n);
    } else {
        int i = (b - ngemm) * blockDim.x + threadIdx.x;
        if (i < e) csr[off[dst[i]] + rank[i]] = (unsigned short)src[i];
    }
}

// one wave per dst node. bf16 rows: quarter-wave (16 lanes x 8 bf16) covers a
// 128-col row -> 4 edges per VMEM, 2-deep unroll -> 8 rows in flight.
// agg[d] = bf16( relu( b + dinv[d] * (xb[d] + sum_e xb[src_e]) ) )
__global__ __launch_bounds__(256) void k_gather128(
    const int* __restrict__ off, const int* __restrict__ deg,
    const unsigned short* __restrict__ csr, const unsigned short* __restrict__ xb,
    const float* __restrict__ dinv, const float* __restrict__ b,
    unsigned short* __restrict__ agg, int n) {
    int wid = (blockIdx.x * blockDim.x + threadIdx.x) >> 6;
    int lane = threadIdx.x & 63;
    if (wid >= n) return;
    const int q = lane >> 4;
    const int c0 = (lane & 15) * 8;

    float a[8];
#pragma unroll
    for (int k = 0; k < 8; ++k) a[k] = 0.f;

    const int s0 = off[wid];
    const int cnt = deg[wid];  // in-degree

    int t = q;
    for (; t + 4 < cnt; t += 8) {
        int e0 = csr[s0 + t];
        int e1 = csr[s0 + t + 4];
        uint4 v0 = *reinterpret_cast<const uint4*>(xb + (size_t)e0 * 128 + c0);
        uint4 v1 = *reinterpret_cast<const uint4*>(xb + (size_t)e1 * 128 + c0);
#pragma unroll
        for (int j = 0; j < 4; ++j) {
            unsigned w0 = (&v0.x)[j];
            unsigned w1 = (&v1.x)[j];
            a[2 * j]     += __uint_as_float(w0 << 16);
            a[2 * j + 1] += __uint_as_float(w0 & 0xffff0000u);
            a[2 * j]     += __uint_as_float(w1 << 16);
            a[2 * j + 1] += __uint_as_float(w1 & 0xffff0000u);
        }
    }
    for (; t < cnt; t += 4) {
        int e0 = csr[s0 + t];
        uint4 v0 = *reinterpret_cast<const uint4*>(xb + (size_t)e0 * 128 + c0);
#pragma unroll
        for (int j = 0; j < 4; ++j) {
            unsigned w0 = (&v0.x)[j];
            a[2 * j]     += __uint_as_float(w0 << 16);
            a[2 * j + 1] += __uint_as_float(w0 & 0xffff0000u);
        }
    }

#pragma unroll
    for (int k = 0; k < 8; ++k) {
        a[k] += __shfl_xor(a[k], 16);
        a[k] += __shfl_xor(a[k], 32);
    }

    if (q == 0) {
        float di = dinv[wid];
        uint4 sv = *reinterpret_cast<const uint4*>(xb + (size_t)wid * 128 + c0);
        float4 bv0 = *reinterpret_cast<const float4*>(b + c0);
        float4 bv1 = *reinterpret_cast<const float4*>(b + c0 + 4);
        float o[8];
#pragma unroll
        for (int j = 0; j < 4; ++j) {
            unsigned w = (&sv.x)[j];
            o[2 * j]     = a[2 * j]     + __uint_as_float(w << 16);
            o[2 * j + 1] = a[2 * j + 1] + __uint_as_float(w & 0xffff0000u);
        }
        const float* bb0 = (const float*)&bv0;
        const float* bb1 = (const float*)&bv1;
        short8 st;
#pragma unroll
        for (int k = 0; k < 8; ++k) {
            float bk = (k < 4) ? bb0[k] : bb1[k - 4];
            st[k] = (short)f2b(fmaxf(fmaf(di, o[k], bk), 0.f));
        }
        *reinterpret_cast<short8*>(agg + (size_t)wid * 128 + c0) = st;
    }
}

// one wave per dst node. bf16 rows of 64 cols: eighth-wave (8 lanes x 8 bf16)
// covers a row -> 8 edges per VMEM; log_softmax fused.
__global__ __launch_bounds__(256) void k_gather64_lsm(
    const int* __restrict__ off, const int* __restrict__ deg,
    const unsigned short* __restrict__ csr, const unsigned short* __restrict__ hb,
    const float* __restrict__ dinv, const float* __restrict__ b,
    float* __restrict__ out, int n) {
    int wid = (blockIdx.x * blockDim.x + threadIdx.x) >> 6;
    int lane = threadIdx.x & 63;
    if (wid >= n) return;
    const int oct = lane >> 3;
    const int c0 = (lane & 7) * 8;

    float a[8];
#pragma unroll
    for (int k = 0; k < 8; ++k) a[k] = 0.f;

    const int s0 = off[wid];
    const int cnt = deg[wid];  // in-degree

    int t = oct;
    for (; t + 8 < cnt; t += 16) {
        int e0 = csr[s0 + t];
        int e1 = csr[s0 + t + 8];
        uint4 v0 = *reinterpret_cast<const uint4*>(hb + (size_t)e0 * 64 + c0);
        uint4 v1 = *reinterpret_cast<const uint4*>(hb + (size_t)e1 * 64 + c0);
#pragma unroll
        for (int j = 0; j < 4; ++j) {
            unsigned w0 = (&v0.x)[j];
            unsigned w1 = (&v1.x)[j];
            a[2 * j]     += __uint_as_float(w0 << 16);
            a[2 * j + 1] += __uint_as_float(w0 & 0xffff0000u);
            a[2 * j]     += __uint_as_float(w1 << 16);
            a[2 * j + 1] += __uint_as_float(w1 & 0xffff0000u);
        }
    }
    for (; t < cnt; t += 8) {
        int e0 = csr[s0 + t];
        uint4 v0 = *reinterpret_cast<const uint4*>(hb + (size_t)e0 * 64 + c0);
#pragma unroll
        for (int j = 0; j < 4; ++j) {
            unsigned w0 = (&v0.x)[j];
            a[2 * j]     += __uint_as_float(w0 << 16);
            a[2 * j + 1] += __uint_as_float(w0 & 0xffff0000u);
        }
    }

#pragma unroll
    for (int k = 0; k < 8; ++k) {
        a[k] += __shfl_xor(a[k], 8);
        a[k] += __shfl_xor(a[k], 16);
        a[k] += __shfl_xor(a[k], 32);
    }

    float di = dinv[wid];
    uint4 sv = *reinterpret_cast<const uint4*>(hb + (size_t)wid * 64 + c0);
    float4 bv0 = *reinterpret_cast<const float4*>(b + c0);
    float4 bv1 = *reinterpret_cast<const float4*>(b + c0 + 4);
    float v[8];
#pragma unroll
    for (int j = 0; j < 4; ++j) {
        unsigned w = (&sv.x)[j];
        v[2 * j]     = a[2 * j]     + __uint_as_float(w << 16);
        v[2 * j + 1] = a[2 * j + 1] + __uint_as_float(w & 0xffff0000u);
    }
    v[0] = fmaf(di, v[0], bv0.x);
    v[1] = fmaf(di, v[1], bv0.y);
    v[2] = fmaf(di, v[2], bv0.z);
    v[3] = fmaf(di, v[3], bv0.w);
    v[4] = fmaf(di, v[4], bv1.x);
    v[5] = fmaf(di, v[5], bv1.y);
    v[6] = fmaf(di, v[6], bv1.z);
    v[7] = fmaf(di, v[7], bv1.w);

    float m = v[0];
#pragma unroll
    for (int k = 1; k < 8; ++k) m = fmaxf(m, v[k]);
    m = fmaxf(m, __shfl_xor(m, 1));
    m = fmaxf(m, __shfl_xor(m, 2));
    m = fmaxf(m, __shfl_xor(m, 4));

    float s = 0.f;
#pragma unroll
    for (int k = 0; k < 8; ++k) s += expf(v[k] - m);
    s += __shfl_xor(s, 1);
    s += __shfl_xor(s, 2);
    s += __shfl_xor(s, 4);
    float ls = m + logf(s);

    if (oct == 0) {
        float4 r0, r1;
        r0.x = v[0] - ls; r0.y = v[1] - ls; r0.z = v[2] - ls; r0.w = v[3] - ls;
        r1.x = v[4] - ls; r1.y = v[5] - ls; r1.z = v[6] - ls; r1.w = v[7] - ls;
        *reinterpret_cast<float4*>(out + (size_t)wid * 64 + c0) = r0;
        *reinterpret_cast<float4*>(out + (size_t)wid * 64 + c0 + 4) = r1;
    }
}

extern "C" void kernel_launch(void* const* d_in, const int* in_sizes, int n_in,
                              void* d_out, int out_size, void* d_ws, size_t ws_size,
                              hipStream_t stream) {
    const float* x  = (const float*)d_in[0];
    const int*   ei = (const int*)d_in[1];
    const float* W1 = (const float*)d_in[2];
    const float* b1 = (const float*)d_in[3];
    const float* W2 = (const float*)d_in[4];
    const float* b2 = (const float*)d_in[5];

    const int n = in_sizes[0] / K1;   // 50000
    const int e = in_sizes[1] / 2;    // 800000
    const int* src = ei;
    const int* dst = ei + e;
    float* out = (float*)d_out;

    const int nb_scan = (n + SCAN_B - 1) / SCAN_B;  // 196 (<=1024)
    const int ngemm = (n + 127) / 128;              // 391 gemm blocks
    const int ncount = (e + 255) / 256;             // 3125 one-edge-per-thread blocks
    const int nwcvt = (128 * 128 + 255) / 256;      // 64 blocks cover both W

    // ws layout (u16 unless noted):
    // agg1[n*128] | xb16[n*128] | hb16[n*64] | deg[n] int | dinv[n] f32 |
    // off[n] int | blocksum int | w1bt[16384] | w2bt[8192] | rank[e] | csr[e]
    unsigned short* agg1     = (unsigned short*)d_ws;
    unsigned short* xb16     = agg1 + (size_t)n * 128;
    unsigned short* hb16     = xb16 + (size_t)n * 128;
    int*            deg      = (int*)(hb16 + (size_t)n * 64);
    float*          dinv     = (float*)(deg + n);
    int*            off      = (int*)(dinv + n);
    int*            blocksum = off + n;
    unsigned short* w1bt     = (unsigned short*)(((uintptr_t)(blocksum + nb_scan) + 15) &
                                                 ~(uintptr_t)15);
    unsigned short* w2bt     = w1bt + 128 * 128;
    unsigned short* rank     = w2bt + 64 * 128;
    unsigned short* csr      = rank + e;

    const int B = 256;

    hipMemsetAsync(deg, 0, (size_t)n * sizeof(int), stream);
    k_count_w<<<nwcvt + ncount, B, 0, stream>>>(dst, e, deg, rank, W1, W2,
                                                w1bt, w2bt, nwcvt);
    k_scan_part<<<nb_scan, SCAN_B, 0, stream>>>(deg, blocksum, n);
    k_scan_top<<<1, 1024, 0, stream>>>(blocksum, nb_scan);
    k_scan_final<<<nb_scan, SCAN_B, 0, stream>>>(deg, blocksum, off, dinv, n);

    // layer-1 MFMA GEMM (blocks first -> co-resident) + one-edge-per-thread fill
    k_gemm_fill<<<ngemm + ncount, B, 0, stream>>>(x, w1bt, dinv, xb16, n,
                                                  src, dst, rank, off, csr, e, ngemm);

    k_gather128<<<(n + 3) / 4, B, 0, stream>>>(off, deg, csr, xb16, dinv, b1, agg1, n);

    k_gemm64<<<ngemm, B, 0, stream>>>(agg1, w2bt, dinv, hb16, n);
    k_gather64_lsm<<<(n + 3) / 4, B, 0, stream>>>(off, deg, csr, hb16, dinv, b2, out, n);
}

// Round 14
// 145.035 us; speedup vs baseline: 1.1668x; 1.0062x over previous
//
#include <hip/hip_runtime.h>

// ---------------------------------------------------------------------------
// 2-layer GCN, CSR-gather, bf16 pre-scaled rows, MFMA GEMMs, atomic-free fill:
// out = log_softmax( Anorm @ relu(Anorm @ (x@W1) + b1) @ W2 + b2 )
// Anorm = D^-1/2 (A+I) D^-1/2.  Row r of each GEMM output is stored as
// bf16(dinv[r] * row); gather sums rows and multiplies by dinv[dst] once.
// CSR build: count pass (rank = atomic return value), scan, then atomic-free
// one-edge-per-thread permutation fill csr[off[dst]+rank] = src (no loops,
// max TLP). Layer-1 MFMA GEMM rides in the fill dispatch, gemm blocks first.
// deg zeroing is a custom kernel (hipMemsetAsync's fill kernel cost 42 us!).
// ---------------------------------------------------------------------------

constexpr int K1 = 128;
constexpr int SCAN_B = 256;

typedef short short8 __attribute__((ext_vector_type(8)));   // 8 bf16
typedef float f32x4 __attribute__((ext_vector_type(4)));

__device__ inline unsigned short f2b(float f) {  // f32 -> bf16 (round-nearest)
    unsigned u = __float_as_uint(f);
    u += 0x7fffu + ((u >> 16) & 1u);
    return (unsigned short)(u >> 16);
}

// one int per thread; replaces hipMemsetAsync (runtime fill kernel = 42 us)
__global__ void k_zero(int* __restrict__ deg, int n) {
    int i = blockIdx.x * blockDim.x + threadIdx.x;
    if (i < n) deg[i] = 0;
}

// W1/W2 transpose+bf16 convert (blocks [0,nwcvt)) fused with the count pass
// (deg = in-degree histogram, rank = per-dst arrival order).
__global__ void k_count_w(const int* __restrict__ dst, int e, int* __restrict__ deg,
                          unsigned short* __restrict__ rank,
                          const float* __restrict__ W1, const float* __restrict__ W2,
                          unsigned short* __restrict__ w1bt,
                          unsigned short* __restrict__ w2bt, int nwcvt) {
    int b = blockIdx.x;
    if (b < nwcvt) {
        int i = b * blockDim.x + threadIdx.x;
        if (i < 128 * 128) {
            int c = i >> 7, k = i & 127;
            w1bt[i] = f2b(W1[k * 128 + c]);
        }
        if (i < 64 * 128) {
            int c = i >> 7, k = i & 127;
            w2bt[i] = f2b(W2[k * 64 + c]);
        }
    } else {
        int i = (b - nwcvt) * blockDim.x + threadIdx.x;
        if (i < e) {
            int p = atomicAdd(&deg[dst[i]], 1);
            rank[i] = (unsigned short)p;
        }
    }
}

__global__ __launch_bounds__(SCAN_B) void k_scan_part(const int* __restrict__ deg,
                                                      int* __restrict__ blocksum, int n) {
    __shared__ int red[SCAN_B];
    int i = blockIdx.x * SCAN_B + threadIdx.x;
    int v = (i < n) ? deg[i] : 0;
    red[threadIdx.x] = v;
    __syncthreads();
    for (int o = SCAN_B / 2; o; o >>= 1) {
        if (threadIdx.x < o) red[threadIdx.x] += red[threadIdx.x + o];
        __syncthreads();
    }
    if (threadIdx.x == 0) blocksum[blockIdx.x] = red[0];
}

__global__ __launch_bounds__(1024) void k_scan_top(int* __restrict__ blocksum, int nb) {
    __shared__ int sh[1024];
    int t = threadIdx.x;
    int v = (t < nb) ? blocksum[t] : 0;
    sh[t] = v;
    __syncthreads();
    for (int o = 1; o < 1024; o <<= 1) {
        int u = (t >= o) ? sh[t - o] : 0;
        __syncthreads();
        sh[t] += u;
        __syncthreads();
    }
    if (t < nb) blocksum[t] = sh[t] - v;  // exclusive
}

__global__ __launch_bounds__(SCAN_B) void k_scan_final(const int* __restrict__ deg,
                                                       const int* __restrict__ blocksum,
                                                       int* __restrict__ off,
                                                       float* __restrict__ dinv, int n) {
    __shared__ int sh[SCAN_B];
    int t = threadIdx.x;
    int i = blockIdx.x * SCAN_B + t;
    int v = (i < n) ? deg[i] : 0;  // in-degree
    sh[t] = v;
    __syncthreads();
    for (int o = 1; o < SCAN_B; o <<= 1) {
        int u = (t >= o) ? sh[t - o] : 0;
        __syncthreads();
        sh[t] += u;
        __syncthreads();
    }
    if (i < n) {
        off[i] = blocksum[blockIdx.x] + sh[t] - v;
        dinv[i] = rsqrtf((float)(v + 1));  // +1 self loop
    }
}

// ---------------------------------------------------------------------------
// MFMA GEMM bodies.  C layout per 16x16x32 mfma: col = lane&15,
// row = (lane>>4)*4 + r.  A frag: row = lane&15, k = (lane>>4)*8 + i.
// ---------------------------------------------------------------------------
// f32 A input: Cb16[n,128] = bf16( dinv[r] * (A[n,128] @ W[128,128]) )
__device__ __forceinline__ void gemm128_body(int bid, const float* __restrict__ A,
                                             const unsigned short* __restrict__ Wbt,
                                             const float* __restrict__ dinv,
                                             unsigned short* __restrict__ Cb, int n) {
    constexpr int NT = 8;
    const int tid = threadIdx.x;
    const int wave = tid >> 6, lane = tid & 63;
    const int rowbase = bid * 128 + wave * 32;
    const int lrow = lane & 15;
    const int kgrp = lane >> 4;

    short8 a[2][4];
#pragma unroll
    for (int s = 0; s < 2; ++s)
#pragma unroll
        for (int kt = 0; kt < 4; ++kt) {
            int R = rowbase + 16 * s + lrow;
            int Rc = (R < n) ? R : (n - 1);
            const float* p = A + (size_t)Rc * 128 + kt * 32 + kgrp * 8;
            float4 u0 = *reinterpret_cast<const float4*>(p);
            float4 u1 = *reinterpret_cast<const float4*>(p + 4);
            short8 af;
            af[0] = (short)f2b(u0.x); af[1] = (short)f2b(u0.y);
            af[2] = (short)f2b(u0.z); af[3] = (short)f2b(u0.w);
            af[4] = (short)f2b(u1.x); af[5] = (short)f2b(u1.y);
            af[6] = (short)f2b(u1.z); af[7] = (short)f2b(u1.w);
            a[s][kt] = af;
        }

    f32x4 acc[2][NT];
#pragma unroll
    for (int s = 0; s < 2; ++s)
#pragma unroll
        for (int nt = 0; nt < NT; ++nt) acc[s][nt] = f32x4{0.f, 0.f, 0.f, 0.f};

#pragma unroll
    for (int nt = 0; nt < NT; ++nt) {
        short8 b[4];
#pragma unroll
        for (int kt = 0; kt < 4; ++kt)
            b[kt] = *reinterpret_cast<const short8*>(
                Wbt + (size_t)(nt * 16 + lrow) * 128 + kt * 32 + kgrp * 8);
#pragma unroll
        for (int s = 0; s < 2; ++s)
#pragma unroll
            for (int kt = 0; kt < 4; ++kt)
                acc[s][nt] = __builtin_amdgcn_mfma_f32_16x16x32_bf16(a[s][kt], b[kt],
                                                                     acc[s][nt], 0, 0, 0);
    }

#pragma unroll
    for (int s = 0; s < 2; ++s)
#pragma unroll
        for (int r = 0; r < 4; ++r) {
            int R = rowbase + 16 * s + kgrp * 4 + r;
            if (R < n) {
                float sc = dinv[R];
#pragma unroll
                for (int nt = 0; nt < NT; ++nt)
                    Cb[(size_t)R * 128 + nt * 16 + lrow] = f2b(sc * acc[s][nt][r]);
            }
        }
}

// bf16 A input (agg1): Cb16[n,64] = bf16( dinv[r] * (Ab[n,128] @ W[128,64]) )
__global__ __launch_bounds__(256) void k_gemm64(
    const unsigned short* __restrict__ Ab, const unsigned short* __restrict__ Wbt,
    const float* __restrict__ dinv, unsigned short* __restrict__ Cb, int n) {
    constexpr int NT = 4;
    const int tid = threadIdx.x;
    const int wave = tid >> 6, lane = tid & 63;
    const int rowbase = blockIdx.x * 128 + wave * 32;
    const int lrow = lane & 15;
    const int kgrp = lane >> 4;

    short8 a[2][4];
#pragma unroll
    for (int s = 0; s < 2; ++s)
#pragma unroll
        for (int kt = 0; kt < 4; ++kt) {
            int R = rowbase + 16 * s + lrow;
            int Rc = (R < n) ? R : (n - 1);
            a[s][kt] = *reinterpret_cast<const short8*>(
                Ab + (size_t)Rc * 128 + kt * 32 + kgrp * 8);
        }

    f32x4 acc[2][NT];
#pragma unroll
    for (int s = 0; s < 2; ++s)
#pragma unroll
        for (int nt = 0; nt < NT; ++nt) acc[s][nt] = f32x4{0.f, 0.f, 0.f, 0.f};

#pragma unroll
    for (int nt = 0; nt < NT; ++nt) {
        short8 b[4];
#pragma unroll
        for (int kt = 0; kt < 4; ++kt)
            b[kt] = *reinterpret_cast<const short8*>(
                Wbt + (size_t)(nt * 16 + lrow) * 128 + kt * 32 + kgrp * 8);
#pragma unroll
        for (int s = 0; s < 2; ++s)
#pragma unroll
            for (int kt = 0; kt < 4; ++kt)
                acc[s][nt] = __builtin_amdgcn_mfma_f32_16x16x32_bf16(a[s][kt], b[kt],
                                                                     acc[s][nt], 0, 0, 0);
    }

#pragma unroll
    for (int s = 0; s < 2; ++s)
#pragma unroll
        for (int r = 0; r < 4; ++r) {
            int R = rowbase + 16 * s + kgrp * 4 + r;
            if (R < n) {
                float sc = dinv[R];
#pragma unroll
                for (int nt = 0; nt < NT; ++nt)
                    Cb[(size_t)R * 64 + nt * 16 + lrow] = f2b(sc * acc[s][nt][r]);
            }
        }
}

// fused: blocks [0,ngemm) do the layer-1 MFMA GEMM (co-resident with fill
// from dispatch 0 -> true overlap); blocks [ngemm,..) do the atomic-free
// one-edge-per-thread permutation fill (no loops, max TLP).
__global__ __launch_bounds__(256) void k_gemm_fill(
    const float* __restrict__ A, const unsigned short* __restrict__ Wbt,
    const float* __restrict__ dinv, unsigned short* __restrict__ Cb, int n,
    const int* __restrict__ src, const int* __restrict__ dst,
    const unsigned short* __restrict__ rank, const int* __restrict__ off,
    unsigned short* __restrict__ csr, int e, int ngemm) {
    int b = blockIdx.x;
    if (b < ngemm) {
        gemm128_body(b, A, Wbt, dinv, Cb, n);
    } else {
        int i = (b - ngemm) * blockDim.x + threadIdx.x;
        if (i < e) csr[off[dst[i]] + rank[i]] = (unsigned short)src[i];
    }
}

// one wave per dst node. bf16 rows: quarter-wave (16 lanes x 8 bf16) covers a
// 128-col row -> 4 edges per VMEM, 2-deep unroll -> 8 rows in flight.
// agg[d] = bf16( relu( b + dinv[d] * (xb[d] + sum_e xb[src_e]) ) )
__global__ __launch_bounds__(256) void k_gather128(
    const int* __restrict__ off, const int* __restrict__ deg,
    const unsigned short* __restrict__ csr, const unsigned short* __restrict__ xb,
    const float* __restrict__ dinv, const float* __restrict__ b,
    unsigned short* __restrict__ agg, int n) {
    int wid = (blockIdx.x * blockDim.x + threadIdx.x) >> 6;
    int lane = threadIdx.x & 63;
    if (wid >= n) return;
    const int q = lane >> 4;
    const int c0 = (lane & 15) * 8;

    float a[8];
#pragma unroll
    for (int k = 0; k < 8; ++k) a[k] = 0.f;

    const int s0 = off[wid];
    const int cnt = deg[wid];  // in-degree

    int t = q;
    for (; t + 4 < cnt; t += 8) {
        int e0 = csr[s0 + t];
        int e1 = csr[s0 + t + 4];
        uint4 v0 = *reinterpret_cast<const uint4*>(xb + (size_t)e0 * 128 + c0);
        uint4 v1 = *reinterpret_cast<const uint4*>(xb + (size_t)e1 * 128 + c0);
#pragma unroll
        for (int j = 0; j < 4; ++j) {
            unsigned w0 = (&v0.x)[j];
            unsigned w1 = (&v1.x)[j];
            a[2 * j]     += __uint_as_float(w0 << 16);
            a[2 * j + 1] += __uint_as_float(w0 & 0xffff0000u);
            a[2 * j]     += __uint_as_float(w1 << 16);
            a[2 * j + 1] += __uint_as_float(w1 & 0xffff0000u);
        }
    }
    for (; t < cnt; t += 4) {
        int e0 = csr[s0 + t];
        uint4 v0 = *reinterpret_cast<const uint4*>(xb + (size_t)e0 * 128 + c0);
#pragma unroll
        for (int j = 0; j < 4; ++j) {
            unsigned w0 = (&v0.x)[j];
            a[2 * j]     += __uint_as_float(w0 << 16);
            a[2 * j + 1] += __uint_as_float(w0 & 0xffff0000u);
        }
    }

#pragma unroll
    for (int k = 0; k < 8; ++k) {
        a[k] += __shfl_xor(a[k], 16);
        a[k] += __shfl_xor(a[k], 32);
    }

    if (q == 0) {
        float di = dinv[wid];
        uint4 sv = *reinterpret_cast<const uint4*>(xb + (size_t)wid * 128 + c0);
        float4 bv0 = *reinterpret_cast<const float4*>(b + c0);
        float4 bv1 = *reinterpret_cast<const float4*>(b + c0 + 4);
        float o[8];
#pragma unroll
        for (int j = 0; j < 4; ++j) {
            unsigned w = (&sv.x)[j];
            o[2 * j]     = a[2 * j]     + __uint_as_float(w << 16);
            o[2 * j + 1] = a[2 * j + 1] + __uint_as_float(w & 0xffff0000u);
        }
        const float* bb0 = (const float*)&bv0;
        const float* bb1 = (const float*)&bv1;
        short8 st;
#pragma unroll
        for (int k = 0; k < 8; ++k) {
            float bk = (k < 4) ? bb0[k] : bb1[k - 4];
            st[k] = (short)f2b(fmaxf(fmaf(di, o[k], bk), 0.f));
        }
        *reinterpret_cast<short8*>(agg + (size_t)wid * 128 + c0) = st;
    }
}

// one wave per dst node. bf16 rows of 64 cols: eighth-wave (8 lanes x 8 bf16)
// covers a row -> 8 edges per VMEM; log_softmax fused.
__global__ __launch_bounds__(256) void k_gather64_lsm(
    const int* __restrict__ off, const int* __restrict__ deg,
    const unsigned short* __restrict__ csr, const unsigned short* __restrict__ hb,
    const float* __restrict__ dinv, const float* __restrict__ b,
    float* __restrict__ out, int n) {
    int wid = (blockIdx.x * blockDim.x + threadIdx.x) >> 6;
    int lane = threadIdx.x & 63;
    if (wid >= n) return;
    const int oct = lane >> 3;
    const int c0 = (lane & 7) * 8;

    float a[8];
#pragma unroll
    for (int k = 0; k < 8; ++k) a[k] = 0.f;

    const int s0 = off[wid];
    const int cnt = deg[wid];  // in-degree

    int t = oct;
    for (; t + 8 < cnt; t += 16) {
        int e0 = csr[s0 + t];
        int e1 = csr[s0 + t + 8];
        uint4 v0 = *reinterpret_cast<const uint4*>(hb + (size_t)e0 * 64 + c0);
        uint4 v1 = *reinterpret_cast<const uint4*>(hb + (size_t)e1 * 64 + c0);
#pragma unroll
        for (int j = 0; j < 4; ++j) {
            unsigned w0 = (&v0.x)[j];
            unsigned w1 = (&v1.x)[j];
            a[2 * j]     += __uint_as_float(w0 << 16);
            a[2 * j + 1] += __uint_as_float(w0 & 0xffff0000u);
            a[2 * j]     += __uint_as_float(w1 << 16);
            a[2 * j + 1] += __uint_as_float(w1 & 0xffff0000u);
        }
    }
    for (; t < cnt; t += 8) {
        int e0 = csr[s0 + t];
        uint4 v0 = *reinterpret_cast<const uint4*>(hb + (size_t)e0 * 64 + c0);
#pragma unroll
        for (int j = 0; j < 4; ++j) {
            unsigned w0 = (&v0.x)[j];
            a[2 * j]     += __uint_as_float(w0 << 16);
            a[2 * j + 1] += __uint_as_float(w0 & 0xffff0000u);
        }
    }

#pragma unroll
    for (int k = 0; k < 8; ++k) {
        a[k] += __shfl_xor(a[k], 8);
        a[k] += __shfl_xor(a[k], 16);
        a[k] += __shfl_xor(a[k], 32);
    }

    float di = dinv[wid];
    uint4 sv = *reinterpret_cast<const uint4*>(hb + (size_t)wid * 64 + c0);
    float4 bv0 = *reinterpret_cast<const float4*>(b + c0);
    float4 bv1 = *reinterpret_cast<const float4*>(b + c0 + 4);
    float v[8];
#pragma unroll
    for (int j = 0; j < 4; ++j) {
        unsigned w = (&sv.x)[j];
        v[2 * j]     = a[2 * j]     + __uint_as_float(w << 16);
        v[2 * j + 1] = a[2 * j + 1] + __uint_as_float(w & 0xffff0000u);
    }
    v[0] = fmaf(di, v[0], bv0.x);
    v[1] = fmaf(di, v[1], bv0.y);
    v[2] = fmaf(di, v[2], bv0.z);
    v[3] = fmaf(di, v[3], bv0.w);
    v[4] = fmaf(di, v[4], bv1.x);
    v[5] = fmaf(di, v[5], bv1.y);
    v[6] = fmaf(di, v[6], bv1.z);
    v[7] = fmaf(di, v[7], bv1.w);

    float m = v[0];
#pragma unroll
    for (int k = 1; k < 8; ++k) m = fmaxf(m, v[k]);
    m = fmaxf(m, __shfl_xor(m, 1));
    m = fmaxf(m, __shfl_xor(m, 2));
    m = fmaxf(m, __shfl_xor(m, 4));

    float s = 0.f;
#pragma unroll
    for (int k = 0; k < 8; ++k) s += expf(v[k] - m);
    s += __shfl_xor(s, 1);
    s += __shfl_xor(s, 2);
    s += __shfl_xor(s, 4);
    float ls = m + logf(s);

    if (oct == 0) {
        float4 r0, r1;
        r0.x = v[0] - ls; r0.y = v[1] - ls; r0.z = v[2] - ls; r0.w = v[3] - ls;
        r1.x = v[4] - ls; r1.y = v[5] - ls; r1.z = v[6] - ls; r1.w = v[7] - ls;
        *reinterpret_cast<float4*>(out + (size_t)wid * 64 + c0) = r0;
        *reinterpret_cast<float4*>(out + (size_t)wid * 64 + c0 + 4) = r1;
    }
}

extern "C" void kernel_launch(void* const* d_in, const int* in_sizes, int n_in,
                              void* d_out, int out_size, void* d_ws, size_t ws_size,
                              hipStream_t stream) {
    const float* x  = (const float*)d_in[0];
    const int*   ei = (const int*)d_in[1];
    const float* W1 = (const float*)d_in[2];
    const float* b1 = (const float*)d_in[3];
    const float* W2 = (const float*)d_in[4];
    const float* b2 = (const float*)d_in[5];

    const int n = in_sizes[0] / K1;   // 50000
    const int e = in_sizes[1] / 2;    // 800000
    const int* src = ei;
    const int* dst = ei + e;
    float* out = (float*)d_out;

    const int nb_scan = (n + SCAN_B - 1) / SCAN_B;  // 196 (<=1024)
    const int ngemm = (n + 127) / 128;              // 391 gemm blocks
    const int ncount = (e + 255) / 256;             // 3125 one-edge-per-thread blocks
    const int nwcvt = (128 * 128 + 255) / 256;      // 64 blocks cover both W

    // ws layout (u16 unless noted):
    // agg1[n*128] | xb16[n*128] | hb16[n*64] | deg[n] int | dinv[n] f32 |
    // off[n] int | blocksum int | w1bt[16384] | w2bt[8192] | rank[e] | csr[e]
    unsigned short* agg1     = (unsigned short*)d_ws;
    unsigned short* xb16     = agg1 + (size_t)n * 128;
    unsigned short* hb16     = xb16 + (size_t)n * 128;
    int*            deg      = (int*)(hb16 + (size_t)n * 64);
    float*          dinv     = (float*)(deg + n);
    int*            off      = (int*)(dinv + n);
    int*            blocksum = off + n;
    unsigned short* w1bt     = (unsigned short*)(((uintptr_t)(blocksum + nb_scan) + 15) &
                                                 ~(uintptr_t)15);
    unsigned short* w2bt     = w1bt + 128 * 128;
    unsigned short* rank     = w2bt + 64 * 128;
    unsigned short* csr      = rank + e;

    const int B = 256;

    k_zero<<<(n + B - 1) / B, B, 0, stream>>>(deg, n);
    k_count_w<<<nwcvt + ncount, B, 0, stream>>>(dst, e, deg, rank, W1, W2,
                                                w1bt, w2bt, nwcvt);
    k_scan_part<<<nb_scan, SCAN_B, 0, stream>>>(deg, blocksum, n);
    k_scan_top<<<1, 1024, 0, stream>>>(blocksum, nb_scan);
    k_scan_final<<<nb_scan, SCAN_B, 0, stream>>>(deg, blocksum, off, dinv, n);

    // layer-1 MFMA GEMM (blocks first -> co-resident) + one-edge-per-thread fill
    k_gemm_fill<<<ngemm + ncount, B, 0, stream>>>(x, w1bt, dinv, xb16, n,
                                                  src, dst, rank, off, csr, e, ngemm);

    k_gather128<<<(n + 3) / 4, B, 0, stream>>>(off, deg, csr, xb16, dinv, b1, agg1, n);

    k_gemm64<<<ngemm, B, 0, stream>>>(agg1, w2bt, dinv, hb16, n);
    k_gather64_lsm<<<(n + 3) / 4, B, 0, stream>>>(off, deg, csr, hb16, dinv, b2, out, n);
}